// Round 12
// baseline (530.047 us; speedup 1.0000x reference)
//
#include <hip/hip_runtime.h>
#include <hip/hip_bf16.h>

#define DIM 32
#define INDIM 5
#define EPB 4096      // edges per block in bucketing passes
#define BKBITS 7
#define BKN 128       // nodes per bucket
#define NBMAX 1024    // max buckets (n <= 131072)
#define CAP 4096      // P2 LDS staging capacity (mean bucket load ~2560)

// bf16 helpers (bit-level, round-to-nearest-even)
__device__ __forceinline__ unsigned short f2bf(float f) {
    unsigned u = __float_as_uint(f);
    u += 0x7FFFu + ((u >> 16) & 1u);
    return (unsigned short)(u >> 16);
}
__device__ __forceinline__ float bf2f_lo(unsigned u) { return __uint_as_float(u << 16); }
__device__ __forceinline__ float bf2f_hi(unsigned u) { return __uint_as_float(u & 0xFFFF0000u); }

// packed accumulate: 8 bf16 dims of one uint4 into 4 float2 accumulators
__device__ __forceinline__ void acc_pk(float2& a01, float2& a23, float2& a45, float2& a67,
                                       uint4 v) {
    float2 v01, v23, v45, v67;
    v01.x = bf2f_lo(v.x); v01.y = bf2f_hi(v.x);
    v23.x = bf2f_lo(v.y); v23.y = bf2f_hi(v.y);
    v45.x = bf2f_lo(v.z); v45.y = bf2f_hi(v.z);
    v67.x = bf2f_lo(v.w); v67.y = bf2f_hi(v.w);
    asm volatile("v_pk_add_f32 %0, %0, %1" : "+v"(a01) : "v"(v01));
    asm volatile("v_pk_add_f32 %0, %0, %1" : "+v"(a23) : "v"(v23));
    asm volatile("v_pk_add_f32 %0, %0, %1" : "+v"(a45) : "v"(v45));
    asm volatile("v_pk_add_f32 %0, %0, %1" : "+v"(a67) : "v"(v67));
}

// ---------------- P0: bucket sizes ----------------

__global__ __launch_bounds__(256) void bucket_count_kernel(const int* __restrict__ dst,
                                                           int* __restrict__ bcnt, int e, int nb) {
    __shared__ int hist[NBMAX];
    int t = threadIdx.x;
    for (int i = t; i < nb; i += 256) hist[i] = 0;
    __syncthreads();
    int base = blockIdx.x * EPB;
    for (int k = 0; k < EPB; k += 256) {
        int i = base + k + t;
        if (i < e) {
            int dv = __builtin_nontemporal_load(&dst[i]);
            atomicAdd(&hist[dv >> BKBITS], 1);
        }
    }
    __syncthreads();
    for (int i = t; i < nb; i += 256) {
        int h = hist[i];
        if (h) atomicAdd(&bcnt[i], h);
    }
}

// ---------------- scan of bucket sizes (single block, 1024 threads) ----------------

__global__ void bucket_scan_kernel(const int* __restrict__ bcnt, int* __restrict__ bbase,
                                   int* __restrict__ bcur, int* __restrict__ row_ptr,
                                   int nb, int n, int e) {
    __shared__ int s[1024];
    int t = threadIdx.x;
    int v = (t < nb) ? bcnt[t] : 0;
    s[t] = v;
    __syncthreads();
    for (int o = 1; o < 1024; o <<= 1) {
        int a = (t >= o) ? s[t - o] : 0;
        __syncthreads();
        s[t] += a;
        __syncthreads();
    }
    if (t < nb) {
        int excl = s[t] - v;
        bbase[t] = excl;
        bcur[t] = excl;
    }
    if (t == 0) {
        bbase[nb] = e;
        row_ptr[n] = e;
    }
}

// ---------------- P1: bucketed scatter of packed edges ----------------
// packed word: (src << BKBITS) | (dst & (BKN-1))

__global__ __launch_bounds__(256) void bucket_fill_kernel(const int* __restrict__ src,
                                                          const int* __restrict__ dst,
                                                          int* __restrict__ bcur,
                                                          unsigned* __restrict__ packed,
                                                          int e, int nb) {
    __shared__ unsigned sw[EPB];
    __shared__ unsigned short sb[EPB];
    __shared__ int hist[NBMAX];
    __shared__ int rbase[NBMAX];
    int t = threadIdx.x;
    for (int i = t; i < nb; i += 256) hist[i] = 0;
    __syncthreads();
    int base = blockIdx.x * EPB;
    for (int k = 0; k < EPB; k += 256) {
        int i = base + k + t;
        if (i < e) {
            int s = __builtin_nontemporal_load(&src[i]);
            int d = __builtin_nontemporal_load(&dst[i]);
            int b = d >> BKBITS;
            sw[k + t] = ((unsigned)s << BKBITS) | (unsigned)(d & (BKN - 1));
            sb[k + t] = (unsigned short)b;
            atomicAdd(&hist[b], 1);
        }
    }
    __syncthreads();
    for (int i = t; i < nb; i += 256) {
        int h = hist[i];
        rbase[i] = h ? atomicAdd(&bcur[i], h) : 0;
        hist[i] = 0;  // reuse as rank counter
    }
    __syncthreads();
    for (int k = 0; k < EPB; k += 256) {
        int i = base + k + t;
        if (i < e) {
            int b = sb[k + t];
            int r = atomicAdd(&hist[b], 1);
            packed[rbase[b] + r] = sw[k + t];
        }
    }
}

// ---------------- P2: per-bucket counting sort -> exact CSR ----------------

__global__ __launch_bounds__(256) void csr_build_kernel(const unsigned* __restrict__ packed,
                                                        const int* __restrict__ bbase,
                                                        int* __restrict__ row_ptr,
                                                        int* __restrict__ esrc, int n) {
    __shared__ unsigned ew[CAP];
    __shared__ int h2[BKN];
    __shared__ int off[BKN];
    int b = blockIdx.x;
    int base = bbase[b];
    int cnt = bbase[b + 1] - base;
    int t = threadIdx.x;
    if (t < BKN) h2[t] = 0;
    __syncthreads();
    bool staged = (cnt <= CAP);
    for (int i = t; i < cnt; i += 256) {
        unsigned w = __builtin_nontemporal_load(&packed[base + i]);
        if (staged) ew[i] = w;
        atomicAdd(&h2[w & (BKN - 1)], 1);
    }
    __syncthreads();
    int v = 0;
    if (t < BKN) {
        v = h2[t];
        off[t] = v;
    }
    __syncthreads();
    for (int o = 1; o < BKN; o <<= 1) {
        int a = 0;
        if (t < BKN && t >= o) a = off[t - o];
        __syncthreads();
        if (t < BKN) off[t] += a;
        __syncthreads();
    }
    if (t < BKN) {
        int excl = off[t] - v;
        off[t] = excl;
        h2[t] = 0;  // reuse as rank counter
    }
    __syncthreads();
    int node = b * BKN + t;
    if (t < BKN && node < n) row_ptr[node] = base + off[t];
    for (int i = t; i < cnt; i += 256) {
        unsigned w = staged ? ew[i] : packed[base + i];
        int dl = w & (BKN - 1);
        int r = atomicAdd(&h2[dl], 1);
        esrc[base + off[dl] + r] = (int)(w >> BKBITS);
    }
}

// ---------------- degree-sorted permutation (256-bin counting sort) ----------------

__global__ __launch_bounds__(256) void deg_hist_kernel(const int* __restrict__ row_ptr,
                                                       int* __restrict__ dhist, int n) {
    __shared__ int lh[256];
    int t = threadIdx.x;
    lh[t] = 0;
    __syncthreads();
    int idx = blockIdx.x * 256 + t;
    if (idx < n) {
        int dg = row_ptr[idx + 1] - row_ptr[idx];
        if (dg > 255) dg = 255;
        atomicAdd(&lh[dg], 1);
    }
    __syncthreads();
    if (lh[t]) atomicAdd(&dhist[t], lh[t]);
}

__global__ void deg_scan_kernel(const int* __restrict__ dhist, int* __restrict__ dcur) {
    __shared__ int s[256];
    int t = threadIdx.x;
    int v = dhist[t];
    s[t] = v;
    __syncthreads();
    for (int o = 1; o < 256; o <<= 1) {
        int a = (t >= o) ? s[t - o] : 0;
        __syncthreads();
        s[t] += a;
        __syncthreads();
    }
    dcur[t] = s[t] - v;  // exclusive
}

__global__ __launch_bounds__(256) void perm_scatter_kernel(const int* __restrict__ row_ptr,
                                                           int* __restrict__ dcur,
                                                           int* __restrict__ perm, int n) {
    int idx = blockIdx.x * 256 + threadIdx.x;
    if (idx < n) {
        int dg = row_ptr[idx + 1] - row_ptr[idx];
        if (dg > 255) dg = 255;
        int pos = atomicAdd(&dcur[dg], 1);
        perm[pos] = idx;
    }
}

// ---------------- input projection: h = x @ w_in.T + b_in (bf16 out) ----------------

__global__ void input_proj_kernel(const float* __restrict__ x, const float* __restrict__ w_in,
                                  const float* __restrict__ b_in,
                                  unsigned short* __restrict__ h, int n) {
    __shared__ float sw[DIM * INDIM];
    __shared__ float sb[DIM];
    int t = threadIdx.x;
    if (t < DIM * INDIM) sw[t] = w_in[t];
    if (t < DIM) sb[t] = b_in[t];
    __syncthreads();
    int idx = blockIdx.x * 256 + t;
    int node = idx >> 5;
    int d = idx & 31;
    if (node < n) {
        const float* xr = x + (size_t)node * INDIM;
        float acc = sb[d];
#pragma unroll
        for (int k = 0; k < INDIM; k++) acc = fmaf(xr[k], sw[d * INDIM + k], acc);
        h[(size_t)node * DIM + d] = f2bf(acc);
    }
}

// ---------------- fused layer: gather-mean + SAGEConv + ReLU + LayerNorm ----------------
// 32 nodes/block (taken through the degree-sorted perm -> degree-uniform waves),
// 128 threads. Phase 1: 4 threads/node, full 16-wide chunks + one masked 16-wide
// tail chunk (invalid lanes load row 0, value cndmask'd to +0). Phase 2: dual
// matvec with both weight matrices in registers, ReLU + LN, direct store.

template <int LAST>
__global__ __launch_bounds__(128, 3) void layer_fused_kernel(
    const int* __restrict__ row_ptr, const int* __restrict__ esrc,
    const int* __restrict__ perm,
    const unsigned short* __restrict__ h_in,
    unsigned short* __restrict__ h_out_bf, float* __restrict__ out_f32,
    const float* __restrict__ wl, const float* __restrict__ bl,
    const float* __restrict__ wr, const float* __restrict__ gamma,
    const float* __restrict__ beta, int n) {
    __shared__ float sAgg[32][DIM];
    __shared__ float sSelf[32][DIM];
    __shared__ int sNode[32];

    int t = threadIdx.x;
    int d = t & 31;

    // ---- phase 1: gather ----
    int nd = t >> 2;  // 0..31
    int q = t & 3;
    int slot = blockIdx.x * 32 + nd;
    const uint4* hv = (const uint4*)h_in;  // row = 4 x uint4 (64 B)

    if (slot < n) {
        int node = perm[slot];
        if (q == 0) sNode[nd] = node;
        {
            uint4 v = hv[(size_t)node * 4 + q];
            float4 f0 = make_float4(bf2f_lo(v.x), bf2f_hi(v.x), bf2f_lo(v.y), bf2f_hi(v.y));
            float4 f1 = make_float4(bf2f_lo(v.z), bf2f_hi(v.z), bf2f_lo(v.w), bf2f_hi(v.w));
            *(float4*)&sSelf[nd][q * 8] = f0;
            *(float4*)&sSelf[nd][q * 8 + 4] = f1;
        }
        int rs = row_ptr[node];
        int re = row_ptr[node + 1];
        float2 a01 = make_float2(0.f, 0.f), a23 = make_float2(0.f, 0.f);
        float2 a45 = make_float2(0.f, 0.f), a67 = make_float2(0.f, 0.f);
        int j = rs;
        // full 16-wide chunks
        for (; j + 16 <= re; j += 16) {
            int ids[16];
#pragma unroll
            for (int k = 0; k < 16; k++) ids[k] = esrc[j + k];
            uint4 vv[16];
#pragma unroll
            for (int k = 0; k < 16; k++) vv[k] = hv[(size_t)ids[k] * 4 + q];
#pragma unroll
            for (int k = 0; k < 16; k++) acc_pk(a01, a23, a45, a67, vv[k]);
        }
        // masked 16-wide tail chunk
        if (j < re) {
            int m = re - j;  // 1..15
            int ids[16];
#pragma unroll
            for (int k = 0; k < 16; k++) ids[k] = (k < m) ? esrc[j + k] : 0;
            uint4 vv[16];
#pragma unroll
            for (int k = 0; k < 16; k++) vv[k] = hv[(size_t)ids[k] * 4 + q];
#pragma unroll
            for (int k = 0; k < 16; k++) {
                uint4 v = vv[k];
                if (k >= m) { v.x = 0u; v.y = 0u; v.z = 0u; v.w = 0u; }  // +0.0 adds
                acc_pk(a01, a23, a45, a67, v);
            }
        }
        float iv = 1.f / fmaxf((float)(re - rs), 1.f);
        float4 f0 = make_float4(a01.x * iv, a01.y * iv, a23.x * iv, a23.y * iv);
        float4 f1 = make_float4(a45.x * iv, a45.y * iv, a67.x * iv, a67.y * iv);
        *(float4*)&sAgg[nd][q * 8] = f0;
        *(float4*)&sAgg[nd][q * 8 + 4] = f1;
    }
    __syncthreads();

    // ---- phase 2: combine + ReLU + LN (weights loaded here, after the barrier) ----
    float wlr[DIM], wrr[DIM];
    {
        const float4* p1 = (const float4*)(wl + (size_t)d * DIM);
        const float4* p2 = (const float4*)(wr + (size_t)d * DIM);
#pragma unroll
        for (int qq = 0; qq < 8; qq++) {
            float4 a = p1[qq];
            wlr[4 * qq] = a.x; wlr[4 * qq + 1] = a.y; wlr[4 * qq + 2] = a.z; wlr[4 * qq + 3] = a.w;
            float4 c = p2[qq];
            wrr[4 * qq] = c.x; wrr[4 * qq + 1] = c.y; wrr[4 * qq + 2] = c.z; wrr[4 * qq + 3] = c.w;
        }
    }
    float bias = bl[d], g = gamma[d], be = beta[d];

#pragma unroll
    for (int it = 0; it < 8; ++it) {
        int ln = it * 4 + (t >> 5);           // local node 0..31
        int slotc = blockIdx.x * 32 + ln;
        if (slotc < n) {
            int nodec = sNode[ln];
            float o = bias;
            const float* va = sAgg[ln];
            const float* vs = sSelf[ln];
#pragma unroll
            for (int qq = 0; qq < 8; qq++) {
                float4 a = *(const float4*)&va[qq * 4];
                float4 s = *(const float4*)&vs[qq * 4];
                o = fmaf(a.x, wlr[4 * qq], o);     o = fmaf(s.x, wrr[4 * qq], o);
                o = fmaf(a.y, wlr[4 * qq + 1], o); o = fmaf(s.y, wrr[4 * qq + 1], o);
                o = fmaf(a.z, wlr[4 * qq + 2], o); o = fmaf(s.z, wrr[4 * qq + 2], o);
                o = fmaf(a.w, wlr[4 * qq + 3], o); o = fmaf(s.w, wrr[4 * qq + 3], o);
            }
            float out = fmaxf(o, 0.f);
            float sum = out, sq = out * out;
#pragma unroll
            for (int off = 16; off > 0; off >>= 1) {
                sum += __shfl_xor(sum, off, 32);
                sq += __shfl_xor(sq, off, 32);
            }
            float mu = sum * (1.f / 32.f);
            float var = fmaxf(sq * (1.f / 32.f) - mu * mu, 0.f);
            float r = rsqrtf(var + 1e-5f);
            float res = (out - mu) * r * g + be;
            if (LAST) out_f32[(size_t)nodec * DIM + d] = res;
            else      h_out_bf[(size_t)nodec * DIM + d] = f2bf(res);
        }
    }
}

// ---------------- launch ----------------

extern "C" void kernel_launch(void* const* d_in, const int* in_sizes, int n_in,
                              void* d_out, int out_size, void* d_ws, size_t ws_size,
                              hipStream_t stream) {
    const float* x = (const float*)d_in[0];
    const int* ei = (const int*)d_in[1];
    const float* w_in = (const float*)d_in[2];
    const float* b_in = (const float*)d_in[3];
    const float* w_l = (const float*)d_in[4];
    const float* b_l = (const float*)d_in[5];
    const float* w_r = (const float*)d_in[6];
    const float* gamma = (const float*)d_in[7];
    const float* beta = (const float*)d_in[8];

    int n = in_sizes[0] / INDIM;
    int e = in_sizes[1] / 2;
    int L = in_sizes[4] / (DIM * DIM);
    const int* src = ei;
    const int* dst = ei + e;
    int nb = (n + BKN - 1) >> BKBITS;  // 128-node buckets (782 for N=100000)

    // workspace carve (~22.1 MB)
    char* w = (char*)d_ws;
    int* bcnt = (int*)w;               w += (size_t)NBMAX * 4;
    int* dhist = (int*)w;              w += 256 * 4;   // adjacent to bcnt: one memset
    int* dcur = (int*)w;               w += 256 * 4;
    int* bbase = (int*)w;              w += (size_t)(NBMAX + 1) * 4;
    int* bcur = (int*)w;               w += (size_t)NBMAX * 4;
    int* row_ptr = (int*)w;            w += (size_t)(n + 1) * 4;
    int* esrc = (int*)w;               w += (size_t)e * 4;
    int* perm = (int*)w;               w += (size_t)n * 4;
    unsigned short* h_A = (unsigned short*)w;  w += (size_t)n * DIM * 2;
    unsigned short* h_B = (unsigned short*)w;  w += (size_t)n * DIM * 2;
    // packed (E*4 = 8 MB) aliases h_A+h_B (12.8 MB): dead before input_proj
    unsigned* packed = (unsigned*)h_A;

    int nbE = (e + EPB - 1) / EPB;
    int nbN = (n + 255) / 256;

    hipMemsetAsync(bcnt, 0, (size_t)NBMAX * 4 + 256 * 4, stream);  // bcnt + dhist
    bucket_count_kernel<<<nbE, 256, 0, stream>>>(dst, bcnt, e, nb);
    bucket_scan_kernel<<<1, 1024, 0, stream>>>(bcnt, bbase, bcur, row_ptr, nb, n, e);
    bucket_fill_kernel<<<nbE, 256, 0, stream>>>(src, dst, bcur, packed, e, nb);
    csr_build_kernel<<<nb, 256, 0, stream>>>(packed, bbase, row_ptr, esrc, n);

    deg_hist_kernel<<<nbN, 256, 0, stream>>>(row_ptr, dhist, n);
    deg_scan_kernel<<<1, 256, 0, stream>>>(dhist, dcur);
    perm_scatter_kernel<<<nbN, 256, 0, stream>>>(row_ptr, dcur, perm, n);

    input_proj_kernel<<<(n * DIM + 255) / 256, 256, 0, stream>>>(x, w_in, b_in, h_A, n);

    // L=3: A->B, B->A, A->d_out
    unsigned short* bufs[2] = {h_A, h_B};
    int nbF = (n + 31) / 32;
    for (int i = 0; i < L; i++) {
        const unsigned short* hin = bufs[i & 1];
        unsigned short* hout = bufs[(i + 1) & 1];
        const float* wl = w_l + (size_t)i * DIM * DIM;
        const float* bl = b_l + (size_t)i * DIM;
        const float* wr = w_r + (size_t)i * DIM * DIM;
        if (i == L - 1)
            layer_fused_kernel<1><<<nbF, 128, 0, stream>>>(row_ptr, esrc, perm, hin, nullptr,
                                                           (float*)d_out, wl, bl, wr,
                                                           gamma, beta, n);
        else
            layer_fused_kernel<0><<<nbF, 128, 0, stream>>>(row_ptr, esrc, perm, hin, hout,
                                                           nullptr, wl, bl, wr,
                                                           gamma, beta, n);
    }
}

// Round 13
// 260.807 us; speedup vs baseline: 2.0323x; 2.0323x over previous
//
#include <hip/hip_runtime.h>
#include <hip/hip_bf16.h>

#define DIM 32
#define INDIM 5
#define EPB 4096      // edges per block in bucketing passes
#define BKBITS 7
#define BKN 128       // nodes per bucket
#define NBMAX 1024    // max buckets (n <= 131072)
#define CAP 4096      // P2 LDS staging capacity (mean bucket load ~2560)

// bf16 helpers (bit-level, round-to-nearest-even)
__device__ __forceinline__ unsigned short f2bf(float f) {
    unsigned u = __float_as_uint(f);
    u += 0x7FFFu + ((u >> 16) & 1u);
    return (unsigned short)(u >> 16);
}
__device__ __forceinline__ float bf2f_lo(unsigned u) { return __uint_as_float(u << 16); }
__device__ __forceinline__ float bf2f_hi(unsigned u) { return __uint_as_float(u & 0xFFFF0000u); }

// packed accumulate: 8 bf16 dims of one uint4 into 4 float2 accumulators
__device__ __forceinline__ void acc_pk(float2& a01, float2& a23, float2& a45, float2& a67,
                                       uint4 v) {
    float2 v01, v23, v45, v67;
    v01.x = bf2f_lo(v.x); v01.y = bf2f_hi(v.x);
    v23.x = bf2f_lo(v.y); v23.y = bf2f_hi(v.y);
    v45.x = bf2f_lo(v.z); v45.y = bf2f_hi(v.z);
    v67.x = bf2f_lo(v.w); v67.y = bf2f_hi(v.w);
    asm volatile("v_pk_add_f32 %0, %0, %1" : "+v"(a01) : "v"(v01));
    asm volatile("v_pk_add_f32 %0, %0, %1" : "+v"(a23) : "v"(v23));
    asm volatile("v_pk_add_f32 %0, %0, %1" : "+v"(a45) : "v"(v45));
    asm volatile("v_pk_add_f32 %0, %0, %1" : "+v"(a67) : "v"(v67));
}

// ---------------- P0: bucket sizes ----------------

__global__ __launch_bounds__(256) void bucket_count_kernel(const int* __restrict__ dst,
                                                           int* __restrict__ bcnt, int e, int nb) {
    __shared__ int hist[NBMAX];
    int t = threadIdx.x;
    for (int i = t; i < nb; i += 256) hist[i] = 0;
    __syncthreads();
    int base = blockIdx.x * EPB;
    for (int k = 0; k < EPB; k += 256) {
        int i = base + k + t;
        if (i < e) {
            int dv = __builtin_nontemporal_load(&dst[i]);
            atomicAdd(&hist[dv >> BKBITS], 1);
        }
    }
    __syncthreads();
    for (int i = t; i < nb; i += 256) {
        int h = hist[i];
        if (h) atomicAdd(&bcnt[i], h);
    }
}

// ---------------- scan of bucket sizes (single block, 1024 threads) ----------------

__global__ void bucket_scan_kernel(const int* __restrict__ bcnt, int* __restrict__ bbase,
                                   int* __restrict__ bcur, int* __restrict__ row_ptr,
                                   int nb, int n, int e) {
    __shared__ int s[1024];
    int t = threadIdx.x;
    int v = (t < nb) ? bcnt[t] : 0;
    s[t] = v;
    __syncthreads();
    for (int o = 1; o < 1024; o <<= 1) {
        int a = (t >= o) ? s[t - o] : 0;
        __syncthreads();
        s[t] += a;
        __syncthreads();
    }
    if (t < nb) {
        int excl = s[t] - v;
        bbase[t] = excl;
        bcur[t] = excl;
    }
    if (t == 0) {
        bbase[nb] = e;
        row_ptr[n] = e;
    }
}

// ---------------- P1: bucketed scatter of packed edges ----------------
// packed word: (src << BKBITS) | (dst & (BKN-1))

__global__ __launch_bounds__(256) void bucket_fill_kernel(const int* __restrict__ src,
                                                          const int* __restrict__ dst,
                                                          int* __restrict__ bcur,
                                                          unsigned* __restrict__ packed,
                                                          int e, int nb) {
    __shared__ unsigned sw[EPB];
    __shared__ unsigned short sb[EPB];
    __shared__ int hist[NBMAX];
    __shared__ int rbase[NBMAX];
    int t = threadIdx.x;
    for (int i = t; i < nb; i += 256) hist[i] = 0;
    __syncthreads();
    int base = blockIdx.x * EPB;
    for (int k = 0; k < EPB; k += 256) {
        int i = base + k + t;
        if (i < e) {
            int s = __builtin_nontemporal_load(&src[i]);
            int d = __builtin_nontemporal_load(&dst[i]);
            int b = d >> BKBITS;
            sw[k + t] = ((unsigned)s << BKBITS) | (unsigned)(d & (BKN - 1));
            sb[k + t] = (unsigned short)b;
            atomicAdd(&hist[b], 1);
        }
    }
    __syncthreads();
    for (int i = t; i < nb; i += 256) {
        int h = hist[i];
        rbase[i] = h ? atomicAdd(&bcur[i], h) : 0;
        hist[i] = 0;  // reuse as rank counter
    }
    __syncthreads();
    for (int k = 0; k < EPB; k += 256) {
        int i = base + k + t;
        if (i < e) {
            int b = sb[k + t];
            int r = atomicAdd(&hist[b], 1);
            packed[rbase[b] + r] = sw[k + t];
        }
    }
}

// ---------------- P2: per-bucket counting sort -> exact CSR ----------------

__global__ __launch_bounds__(256) void csr_build_kernel(const unsigned* __restrict__ packed,
                                                        const int* __restrict__ bbase,
                                                        int* __restrict__ row_ptr,
                                                        int* __restrict__ esrc, int n) {
    __shared__ unsigned ew[CAP];
    __shared__ int h2[BKN];
    __shared__ int off[BKN];
    int b = blockIdx.x;
    int base = bbase[b];
    int cnt = bbase[b + 1] - base;
    int t = threadIdx.x;
    if (t < BKN) h2[t] = 0;
    __syncthreads();
    bool staged = (cnt <= CAP);
    for (int i = t; i < cnt; i += 256) {
        unsigned w = __builtin_nontemporal_load(&packed[base + i]);
        if (staged) ew[i] = w;
        atomicAdd(&h2[w & (BKN - 1)], 1);
    }
    __syncthreads();
    int v = 0;
    if (t < BKN) {
        v = h2[t];
        off[t] = v;
    }
    __syncthreads();
    for (int o = 1; o < BKN; o <<= 1) {
        int a = 0;
        if (t < BKN && t >= o) a = off[t - o];
        __syncthreads();
        if (t < BKN) off[t] += a;
        __syncthreads();
    }
    if (t < BKN) {
        int excl = off[t] - v;
        off[t] = excl;
        h2[t] = 0;  // reuse as rank counter
    }
    __syncthreads();
    int node = b * BKN + t;
    if (t < BKN && node < n) row_ptr[node] = base + off[t];
    for (int i = t; i < cnt; i += 256) {
        unsigned w = staged ? ew[i] : packed[base + i];
        int dl = w & (BKN - 1);
        int r = atomicAdd(&h2[dl], 1);
        esrc[base + off[dl] + r] = (int)(w >> BKBITS);
    }
}

// ---------------- degree-sorted permutation (256-bin counting sort) ----------------

__global__ __launch_bounds__(256) void deg_hist_kernel(const int* __restrict__ row_ptr,
                                                       int* __restrict__ dhist, int n) {
    __shared__ int lh[256];
    int t = threadIdx.x;
    lh[t] = 0;
    __syncthreads();
    int idx = blockIdx.x * 256 + t;
    if (idx < n) {
        int dg = row_ptr[idx + 1] - row_ptr[idx];
        if (dg > 255) dg = 255;
        atomicAdd(&lh[dg], 1);
    }
    __syncthreads();
    if (lh[t]) atomicAdd(&dhist[t], lh[t]);
}

__global__ void deg_scan_kernel(const int* __restrict__ dhist, int* __restrict__ dcur) {
    __shared__ int s[256];
    int t = threadIdx.x;
    int v = dhist[t];
    s[t] = v;
    __syncthreads();
    for (int o = 1; o < 256; o <<= 1) {
        int a = (t >= o) ? s[t - o] : 0;
        __syncthreads();
        s[t] += a;
        __syncthreads();
    }
    dcur[t] = s[t] - v;  // exclusive
}

// two-level scatter: per-block LDS histogram -> one global atomic per (block,bin)
// -> in-block rank via LDS atomics -> write. Avoids the 100K-into-40-bins
// global-atomic contention that cost 274 us.
__global__ __launch_bounds__(256) void perm_scatter_kernel(const int* __restrict__ row_ptr,
                                                           int* __restrict__ dcur,
                                                           int* __restrict__ perm, int n) {
    __shared__ int lh[256];     // local histogram / rank counter
    __shared__ int lbase[256];  // reserved global base per bin
    int t = threadIdx.x;
    lh[t] = 0;
    __syncthreads();
    int idx = blockIdx.x * 256 + t;
    int dg = -1;
    if (idx < n) {
        dg = row_ptr[idx + 1] - row_ptr[idx];
        if (dg > 255) dg = 255;
        atomicAdd(&lh[dg], 1);
    }
    __syncthreads();
    int h = lh[t];
    lbase[t] = h ? atomicAdd(&dcur[t], h) : 0;
    lh[t] = 0;  // reuse as rank counter
    __syncthreads();
    if (idx < n) {
        int r = atomicAdd(&lh[dg], 1);
        perm[lbase[dg] + r] = idx;
    }
}

// ---------------- input projection: h = x @ w_in.T + b_in (bf16 out) ----------------

__global__ void input_proj_kernel(const float* __restrict__ x, const float* __restrict__ w_in,
                                  const float* __restrict__ b_in,
                                  unsigned short* __restrict__ h, int n) {
    __shared__ float sw[DIM * INDIM];
    __shared__ float sb[DIM];
    int t = threadIdx.x;
    if (t < DIM * INDIM) sw[t] = w_in[t];
    if (t < DIM) sb[t] = b_in[t];
    __syncthreads();
    int idx = blockIdx.x * 256 + t;
    int node = idx >> 5;
    int d = idx & 31;
    if (node < n) {
        const float* xr = x + (size_t)node * INDIM;
        float acc = sb[d];
#pragma unroll
        for (int k = 0; k < INDIM; k++) acc = fmaf(xr[k], sw[d * INDIM + k], acc);
        h[(size_t)node * DIM + d] = f2bf(acc);
    }
}

// ---------------- fused layer: gather-mean + SAGEConv + ReLU + LayerNorm ----------------
// 32 nodes/block (via degree-sorted perm -> degree-uniform waves), 128 threads.
// Phase 1: 4 threads/node, full 16-wide chunks + masked 16-wide tail.
// Phase 2: dual matvec with weights in registers, ReLU + LN, direct store.

template <int LAST>
__global__ __launch_bounds__(128, 3) void layer_fused_kernel(
    const int* __restrict__ row_ptr, const int* __restrict__ esrc,
    const int* __restrict__ perm,
    const unsigned short* __restrict__ h_in,
    unsigned short* __restrict__ h_out_bf, float* __restrict__ out_f32,
    const float* __restrict__ wl, const float* __restrict__ bl,
    const float* __restrict__ wr, const float* __restrict__ gamma,
    const float* __restrict__ beta, int n) {
    __shared__ float sAgg[32][DIM];
    __shared__ float sSelf[32][DIM];
    __shared__ int sNode[32];

    int t = threadIdx.x;
    int d = t & 31;

    // ---- phase 1: gather ----
    int nd = t >> 2;  // 0..31
    int q = t & 3;
    int slot = blockIdx.x * 32 + nd;
    const uint4* hv = (const uint4*)h_in;  // row = 4 x uint4 (64 B)

    if (slot < n) {
        int node = perm[slot];
        if (q == 0) sNode[nd] = node;
        {
            uint4 v = hv[(size_t)node * 4 + q];
            float4 f0 = make_float4(bf2f_lo(v.x), bf2f_hi(v.x), bf2f_lo(v.y), bf2f_hi(v.y));
            float4 f1 = make_float4(bf2f_lo(v.z), bf2f_hi(v.z), bf2f_lo(v.w), bf2f_hi(v.w));
            *(float4*)&sSelf[nd][q * 8] = f0;
            *(float4*)&sSelf[nd][q * 8 + 4] = f1;
        }
        int rs = row_ptr[node];
        int re = row_ptr[node + 1];
        float2 a01 = make_float2(0.f, 0.f), a23 = make_float2(0.f, 0.f);
        float2 a45 = make_float2(0.f, 0.f), a67 = make_float2(0.f, 0.f);
        int j = rs;
        for (; j + 16 <= re; j += 16) {
            int ids[16];
#pragma unroll
            for (int k = 0; k < 16; k++) ids[k] = esrc[j + k];
            uint4 vv[16];
#pragma unroll
            for (int k = 0; k < 16; k++) vv[k] = hv[(size_t)ids[k] * 4 + q];
#pragma unroll
            for (int k = 0; k < 16; k++) acc_pk(a01, a23, a45, a67, vv[k]);
        }
        if (j < re) {
            int m = re - j;  // 1..15
            int ids[16];
#pragma unroll
            for (int k = 0; k < 16; k++) ids[k] = (k < m) ? esrc[j + k] : 0;
            uint4 vv[16];
#pragma unroll
            for (int k = 0; k < 16; k++) vv[k] = hv[(size_t)ids[k] * 4 + q];
#pragma unroll
            for (int k = 0; k < 16; k++) {
                uint4 v = vv[k];
                if (k >= m) { v.x = 0u; v.y = 0u; v.z = 0u; v.w = 0u; }  // +0.0 adds
                acc_pk(a01, a23, a45, a67, v);
            }
        }
        float iv = 1.f / fmaxf((float)(re - rs), 1.f);
        float4 f0 = make_float4(a01.x * iv, a01.y * iv, a23.x * iv, a23.y * iv);
        float4 f1 = make_float4(a45.x * iv, a45.y * iv, a67.x * iv, a67.y * iv);
        *(float4*)&sAgg[nd][q * 8] = f0;
        *(float4*)&sAgg[nd][q * 8 + 4] = f1;
    }
    __syncthreads();

    // ---- phase 2: combine + ReLU + LN (weights loaded here, after the barrier) ----
    float wlr[DIM], wrr[DIM];
    {
        const float4* p1 = (const float4*)(wl + (size_t)d * DIM);
        const float4* p2 = (const float4*)(wr + (size_t)d * DIM);
#pragma unroll
        for (int qq = 0; qq < 8; qq++) {
            float4 a = p1[qq];
            wlr[4 * qq] = a.x; wlr[4 * qq + 1] = a.y; wlr[4 * qq + 2] = a.z; wlr[4 * qq + 3] = a.w;
            float4 c = p2[qq];
            wrr[4 * qq] = c.x; wrr[4 * qq + 1] = c.y; wrr[4 * qq + 2] = c.z; wrr[4 * qq + 3] = c.w;
        }
    }
    float bias = bl[d], g = gamma[d], be = beta[d];

#pragma unroll
    for (int it = 0; it < 8; ++it) {
        int ln = it * 4 + (t >> 5);           // local node 0..31
        int slotc = blockIdx.x * 32 + ln;
        if (slotc < n) {
            int nodec = sNode[ln];
            float o = bias;
            const float* va = sAgg[ln];
            const float* vs = sSelf[ln];
#pragma unroll
            for (int qq = 0; qq < 8; qq++) {
                float4 a = *(const float4*)&va[qq * 4];
                float4 s = *(const float4*)&vs[qq * 4];
                o = fmaf(a.x, wlr[4 * qq], o);     o = fmaf(s.x, wrr[4 * qq], o);
                o = fmaf(a.y, wlr[4 * qq + 1], o); o = fmaf(s.y, wrr[4 * qq + 1], o);
                o = fmaf(a.z, wlr[4 * qq + 2], o); o = fmaf(s.z, wrr[4 * qq + 2], o);
                o = fmaf(a.w, wlr[4 * qq + 3], o); o = fmaf(s.w, wrr[4 * qq + 3], o);
            }
            float out = fmaxf(o, 0.f);
            float sum = out, sq = out * out;
#pragma unroll
            for (int off = 16; off > 0; off >>= 1) {
                sum += __shfl_xor(sum, off, 32);
                sq += __shfl_xor(sq, off, 32);
            }
            float mu = sum * (1.f / 32.f);
            float var = fmaxf(sq * (1.f / 32.f) - mu * mu, 0.f);
            float r = rsqrtf(var + 1e-5f);
            float res = (out - mu) * r * g + be;
            if (LAST) out_f32[(size_t)nodec * DIM + d] = res;
            else      h_out_bf[(size_t)nodec * DIM + d] = f2bf(res);
        }
    }
}

// ---------------- launch ----------------

extern "C" void kernel_launch(void* const* d_in, const int* in_sizes, int n_in,
                              void* d_out, int out_size, void* d_ws, size_t ws_size,
                              hipStream_t stream) {
    const float* x = (const float*)d_in[0];
    const int* ei = (const int*)d_in[1];
    const float* w_in = (const float*)d_in[2];
    const float* b_in = (const float*)d_in[3];
    const float* w_l = (const float*)d_in[4];
    const float* b_l = (const float*)d_in[5];
    const float* w_r = (const float*)d_in[6];
    const float* gamma = (const float*)d_in[7];
    const float* beta = (const float*)d_in[8];

    int n = in_sizes[0] / INDIM;
    int e = in_sizes[1] / 2;
    int L = in_sizes[4] / (DIM * DIM);
    const int* src = ei;
    const int* dst = ei + e;
    int nb = (n + BKN - 1) >> BKBITS;  // 128-node buckets (782 for N=100000)

    // workspace carve (~22.1 MB)
    char* w = (char*)d_ws;
    int* bcnt = (int*)w;               w += (size_t)NBMAX * 4;
    int* dhist = (int*)w;              w += 256 * 4;   // adjacent to bcnt: one memset
    int* dcur = (int*)w;               w += 256 * 4;
    int* bbase = (int*)w;              w += (size_t)(NBMAX + 1) * 4;
    int* bcur = (int*)w;               w += (size_t)NBMAX * 4;
    int* row_ptr = (int*)w;            w += (size_t)(n + 1) * 4;
    int* esrc = (int*)w;               w += (size_t)e * 4;
    int* perm = (int*)w;               w += (size_t)n * 4;
    unsigned short* h_A = (unsigned short*)w;  w += (size_t)n * DIM * 2;
    unsigned short* h_B = (unsigned short*)w;  w += (size_t)n * DIM * 2;
    // packed (E*4 = 8 MB) aliases h_A+h_B (12.8 MB): dead before input_proj
    unsigned* packed = (unsigned*)h_A;

    int nbE = (e + EPB - 1) / EPB;
    int nbN = (n + 255) / 256;

    hipMemsetAsync(bcnt, 0, (size_t)NBMAX * 4 + 256 * 4, stream);  // bcnt + dhist
    bucket_count_kernel<<<nbE, 256, 0, stream>>>(dst, bcnt, e, nb);
    bucket_scan_kernel<<<1, 1024, 0, stream>>>(bcnt, bbase, bcur, row_ptr, nb, n, e);
    bucket_fill_kernel<<<nbE, 256, 0, stream>>>(src, dst, bcur, packed, e, nb);
    csr_build_kernel<<<nb, 256, 0, stream>>>(packed, bbase, row_ptr, esrc, n);

    deg_hist_kernel<<<nbN, 256, 0, stream>>>(row_ptr, dhist, n);
    deg_scan_kernel<<<1, 256, 0, stream>>>(dhist, dcur);
    perm_scatter_kernel<<<nbN, 256, 0, stream>>>(row_ptr, dcur, perm, n);

    input_proj_kernel<<<(n * DIM + 255) / 256, 256, 0, stream>>>(x, w_in, b_in, h_A, n);

    // L=3: A->B, B->A, A->d_out
    unsigned short* bufs[2] = {h_A, h_B};
    int nbF = (n + 31) / 32;
    for (int i = 0; i < L; i++) {
        const unsigned short* hin = bufs[i & 1];
        unsigned short* hout = bufs[(i + 1) & 1];
        const float* wl = w_l + (size_t)i * DIM * DIM;
        const float* bl = b_l + (size_t)i * DIM;
        const float* wr = w_r + (size_t)i * DIM * DIM;
        if (i == L - 1)
            layer_fused_kernel<1><<<nbF, 128, 0, stream>>>(row_ptr, esrc, perm, hin, nullptr,
                                                           (float*)d_out, wl, bl, wr,
                                                           gamma, beta, n);
        else
            layer_fused_kernel<0><<<nbF, 128, 0, stream>>>(row_ptr, esrc, perm, hin, hout,
                                                           nullptr, wl, bl, wr,
                                                           gamma, beta, n);
    }
}

// Round 14
// 254.474 us; speedup vs baseline: 2.0829x; 1.0249x over previous
//
#include <hip/hip_runtime.h>
#include <hip/hip_bf16.h>

#define DIM 32
#define INDIM 5
#define EPB 4096      // edges per block in bucketing passes
#define BKBITS 7
#define BKN 128       // nodes per bucket
#define NBMAX 1024    // max buckets (n <= 131072)
#define CAP 4096      // P2 LDS staging capacity (mean bucket load ~2560)

// bf16 helpers (bit-level, round-to-nearest-even)
__device__ __forceinline__ unsigned short f2bf(float f) {
    unsigned u = __float_as_uint(f);
    u += 0x7FFFu + ((u >> 16) & 1u);
    return (unsigned short)(u >> 16);
}
__device__ __forceinline__ float bf2f_lo(unsigned u) { return __uint_as_float(u << 16); }
__device__ __forceinline__ float bf2f_hi(unsigned u) { return __uint_as_float(u & 0xFFFF0000u); }

// packed accumulate: 8 bf16 dims of one uint4 into 4 float2 accumulators
__device__ __forceinline__ void acc_pk(float2& a01, float2& a23, float2& a45, float2& a67,
                                       uint4 v) {
    float2 v01, v23, v45, v67;
    v01.x = bf2f_lo(v.x); v01.y = bf2f_hi(v.x);
    v23.x = bf2f_lo(v.y); v23.y = bf2f_hi(v.y);
    v45.x = bf2f_lo(v.z); v45.y = bf2f_hi(v.z);
    v67.x = bf2f_lo(v.w); v67.y = bf2f_hi(v.w);
    asm volatile("v_pk_add_f32 %0, %0, %1" : "+v"(a01) : "v"(v01));
    asm volatile("v_pk_add_f32 %0, %0, %1" : "+v"(a23) : "v"(v23));
    asm volatile("v_pk_add_f32 %0, %0, %1" : "+v"(a45) : "v"(v45));
    asm volatile("v_pk_add_f32 %0, %0, %1" : "+v"(a67) : "v"(v67));
}

// ---------------- P0: bucket sizes ----------------

__global__ __launch_bounds__(256) void bucket_count_kernel(const int* __restrict__ dst,
                                                           int* __restrict__ bcnt, int e, int nb) {
    __shared__ int hist[NBMAX];
    int t = threadIdx.x;
    for (int i = t; i < nb; i += 256) hist[i] = 0;
    __syncthreads();
    int base = blockIdx.x * EPB;
    for (int k = 0; k < EPB; k += 256) {
        int i = base + k + t;
        if (i < e) {
            int dv = __builtin_nontemporal_load(&dst[i]);
            atomicAdd(&hist[dv >> BKBITS], 1);
        }
    }
    __syncthreads();
    for (int i = t; i < nb; i += 256) {
        int h = hist[i];
        if (h) atomicAdd(&bcnt[i], h);
    }
}

// ---------------- scan of bucket sizes (single block, 1024 threads) ----------------

__global__ void bucket_scan_kernel(const int* __restrict__ bcnt, int* __restrict__ bbase,
                                   int* __restrict__ bcur, int* __restrict__ row_ptr,
                                   int nb, int n, int e) {
    __shared__ int s[1024];
    int t = threadIdx.x;
    int v = (t < nb) ? bcnt[t] : 0;
    s[t] = v;
    __syncthreads();
    for (int o = 1; o < 1024; o <<= 1) {
        int a = (t >= o) ? s[t - o] : 0;
        __syncthreads();
        s[t] += a;
        __syncthreads();
    }
    if (t < nb) {
        int excl = s[t] - v;
        bbase[t] = excl;
        bcur[t] = excl;
    }
    if (t == 0) {
        bbase[nb] = e;
        row_ptr[n] = e;
    }
}

// ---------------- P1: bucketed scatter of packed edges ----------------
// packed word: (src << BKBITS) | (dst & (BKN-1))

__global__ __launch_bounds__(256) void bucket_fill_kernel(const int* __restrict__ src,
                                                          const int* __restrict__ dst,
                                                          int* __restrict__ bcur,
                                                          unsigned* __restrict__ packed,
                                                          int e, int nb) {
    __shared__ unsigned sw[EPB];
    __shared__ unsigned short sb[EPB];
    __shared__ int hist[NBMAX];
    __shared__ int rbase[NBMAX];
    int t = threadIdx.x;
    for (int i = t; i < nb; i += 256) hist[i] = 0;
    __syncthreads();
    int base = blockIdx.x * EPB;
    for (int k = 0; k < EPB; k += 256) {
        int i = base + k + t;
        if (i < e) {
            int s = __builtin_nontemporal_load(&src[i]);
            int d = __builtin_nontemporal_load(&dst[i]);
            int b = d >> BKBITS;
            sw[k + t] = ((unsigned)s << BKBITS) | (unsigned)(d & (BKN - 1));
            sb[k + t] = (unsigned short)b;
            atomicAdd(&hist[b], 1);
        }
    }
    __syncthreads();
    for (int i = t; i < nb; i += 256) {
        int h = hist[i];
        rbase[i] = h ? atomicAdd(&bcur[i], h) : 0;
        hist[i] = 0;  // reuse as rank counter
    }
    __syncthreads();
    for (int k = 0; k < EPB; k += 256) {
        int i = base + k + t;
        if (i < e) {
            int b = sb[k + t];
            int r = atomicAdd(&hist[b], 1);
            packed[rbase[b] + r] = sw[k + t];
        }
    }
}

// ---------------- P2: per-bucket counting sort -> exact CSR ----------------

__global__ __launch_bounds__(256) void csr_build_kernel(const unsigned* __restrict__ packed,
                                                        const int* __restrict__ bbase,
                                                        int* __restrict__ row_ptr,
                                                        int* __restrict__ esrc, int n) {
    __shared__ unsigned ew[CAP];
    __shared__ int h2[BKN];
    __shared__ int off[BKN];
    int b = blockIdx.x;
    int base = bbase[b];
    int cnt = bbase[b + 1] - base;
    int t = threadIdx.x;
    if (t < BKN) h2[t] = 0;
    __syncthreads();
    bool staged = (cnt <= CAP);
    for (int i = t; i < cnt; i += 256) {
        unsigned w = __builtin_nontemporal_load(&packed[base + i]);
        if (staged) ew[i] = w;
        atomicAdd(&h2[w & (BKN - 1)], 1);
    }
    __syncthreads();
    int v = 0;
    if (t < BKN) {
        v = h2[t];
        off[t] = v;
    }
    __syncthreads();
    for (int o = 1; o < BKN; o <<= 1) {
        int a = 0;
        if (t < BKN && t >= o) a = off[t - o];
        __syncthreads();
        if (t < BKN) off[t] += a;
        __syncthreads();
    }
    if (t < BKN) {
        int excl = off[t] - v;
        off[t] = excl;
        h2[t] = 0;  // reuse as rank counter
    }
    __syncthreads();
    int node = b * BKN + t;
    if (t < BKN && node < n) row_ptr[node] = base + off[t];
    for (int i = t; i < cnt; i += 256) {
        unsigned w = staged ? ew[i] : packed[base + i];
        int dl = w & (BKN - 1);
        int r = atomicAdd(&h2[dl], 1);
        esrc[base + off[dl] + r] = (int)(w >> BKBITS);
    }
}

// ---------------- input projection: h = x @ w_in.T + b_in (bf16 out) ----------------

__global__ void input_proj_kernel(const float* __restrict__ x, const float* __restrict__ w_in,
                                  const float* __restrict__ b_in,
                                  unsigned short* __restrict__ h, int n) {
    __shared__ float sw[DIM * INDIM];
    __shared__ float sb[DIM];
    int t = threadIdx.x;
    if (t < DIM * INDIM) sw[t] = w_in[t];
    if (t < DIM) sb[t] = b_in[t];
    __syncthreads();
    int idx = blockIdx.x * 256 + t;
    int node = idx >> 5;
    int d = idx & 31;
    if (node < n) {
        const float* xr = x + (size_t)node * INDIM;
        float acc = sb[d];
#pragma unroll
        for (int k = 0; k < INDIM; k++) acc = fmaf(xr[k], sw[d * INDIM + k], acc);
        h[(size_t)node * DIM + d] = f2bf(acc);
    }
}

// ---------------- fused layer: gather-mean + SAGEConv + ReLU + LayerNorm ----------------
// 16 nodes/block, 64 threads (1 wave) -> max block-level concurrency.
// Phase 1: 4 threads/node (thread q owns dims [8q,8q+8)), 16-wide gather chunks
// + masked 16-wide tail; esrc loads nontemporal (protect L2 for h rows).
// Phase 2: dual matvec with both weight matrices in registers, ReLU + LN,
// nontemporal direct store.

template <int LAST>
__global__ __launch_bounds__(64, 4) void layer_fused_kernel(
    const int* __restrict__ row_ptr, const int* __restrict__ esrc,
    const unsigned short* __restrict__ h_in,
    unsigned short* __restrict__ h_out_bf, float* __restrict__ out_f32,
    const float* __restrict__ wl, const float* __restrict__ bl,
    const float* __restrict__ wr, const float* __restrict__ gamma,
    const float* __restrict__ beta, int n) {
    __shared__ float sAgg[16][DIM];
    __shared__ float sSelf[16][DIM];

    int t = threadIdx.x;
    int d = t & 31;

    // ---- phase 1: gather ----
    int nd = t >> 2;  // 0..15
    int q = t & 3;
    int node = blockIdx.x * 16 + nd;
    const uint4* hv = (const uint4*)h_in;  // row = 4 x uint4 (64 B)

    if (node < n) {
        {
            uint4 v = hv[(size_t)node * 4 + q];
            float4 f0 = make_float4(bf2f_lo(v.x), bf2f_hi(v.x), bf2f_lo(v.y), bf2f_hi(v.y));
            float4 f1 = make_float4(bf2f_lo(v.z), bf2f_hi(v.z), bf2f_lo(v.w), bf2f_hi(v.w));
            *(float4*)&sSelf[nd][q * 8] = f0;
            *(float4*)&sSelf[nd][q * 8 + 4] = f1;
        }
        int rs = row_ptr[node];
        int re = row_ptr[node + 1];
        float2 a01 = make_float2(0.f, 0.f), a23 = make_float2(0.f, 0.f);
        float2 a45 = make_float2(0.f, 0.f), a67 = make_float2(0.f, 0.f);
        int j = rs;
        for (; j + 16 <= re; j += 16) {
            int ids[16];
#pragma unroll
            for (int k = 0; k < 16; k++) ids[k] = __builtin_nontemporal_load(&esrc[j + k]);
            uint4 vv[16];
#pragma unroll
            for (int k = 0; k < 16; k++) vv[k] = hv[(size_t)ids[k] * 4 + q];
#pragma unroll
            for (int k = 0; k < 16; k++) acc_pk(a01, a23, a45, a67, vv[k]);
        }
        if (j < re) {
            int m = re - j;  // 1..15
            int ids[16];
#pragma unroll
            for (int k = 0; k < 16; k++) ids[k] = (k < m) ? __builtin_nontemporal_load(&esrc[j + k]) : 0;
            uint4 vv[16];
#pragma unroll
            for (int k = 0; k < 16; k++) vv[k] = hv[(size_t)ids[k] * 4 + q];
#pragma unroll
            for (int k = 0; k < 16; k++) {
                uint4 v = vv[k];
                if (k >= m) { v.x = 0u; v.y = 0u; v.z = 0u; v.w = 0u; }  // +0.0 adds
                acc_pk(a01, a23, a45, a67, v);
            }
        }
        float iv = 1.f / fmaxf((float)(re - rs), 1.f);
        float4 f0 = make_float4(a01.x * iv, a01.y * iv, a23.x * iv, a23.y * iv);
        float4 f1 = make_float4(a45.x * iv, a45.y * iv, a67.x * iv, a67.y * iv);
        *(float4*)&sAgg[nd][q * 8] = f0;
        *(float4*)&sAgg[nd][q * 8 + 4] = f1;
    }
    __syncthreads();

    // ---- phase 2: combine + ReLU + LN (weights loaded here, after the barrier) ----
    float wlr[DIM], wrr[DIM];
    {
        const float4* p1 = (const float4*)(wl + (size_t)d * DIM);
        const float4* p2 = (const float4*)(wr + (size_t)d * DIM);
#pragma unroll
        for (int qq = 0; qq < 8; qq++) {
            float4 a = p1[qq];
            wlr[4 * qq] = a.x; wlr[4 * qq + 1] = a.y; wlr[4 * qq + 2] = a.z; wlr[4 * qq + 3] = a.w;
            float4 c = p2[qq];
            wrr[4 * qq] = c.x; wrr[4 * qq + 1] = c.y; wrr[4 * qq + 2] = c.z; wrr[4 * qq + 3] = c.w;
        }
    }
    float bias = bl[d], g = gamma[d], be = beta[d];

#pragma unroll
    for (int it = 0; it < 8; ++it) {
        int ln = it * 2 + (t >> 5);           // local node 0..15
        int nodec = blockIdx.x * 16 + ln;
        if (nodec < n) {
            float o = bias;
            const float* va = sAgg[ln];
            const float* vs = sSelf[ln];
#pragma unroll
            for (int qq = 0; qq < 8; qq++) {
                float4 a = *(const float4*)&va[qq * 4];
                float4 s = *(const float4*)&vs[qq * 4];
                o = fmaf(a.x, wlr[4 * qq], o);     o = fmaf(s.x, wrr[4 * qq], o);
                o = fmaf(a.y, wlr[4 * qq + 1], o); o = fmaf(s.y, wrr[4 * qq + 1], o);
                o = fmaf(a.z, wlr[4 * qq + 2], o); o = fmaf(s.z, wrr[4 * qq + 2], o);
                o = fmaf(a.w, wlr[4 * qq + 3], o); o = fmaf(s.w, wrr[4 * qq + 3], o);
            }
            float out = fmaxf(o, 0.f);
            float sum = out, sq = out * out;
#pragma unroll
            for (int off = 16; off > 0; off >>= 1) {
                sum += __shfl_xor(sum, off, 32);
                sq += __shfl_xor(sq, off, 32);
            }
            float mu = sum * (1.f / 32.f);
            float var = fmaxf(sq * (1.f / 32.f) - mu * mu, 0.f);
            float r = rsqrtf(var + 1e-5f);
            float res = (out - mu) * r * g + be;
            if (LAST) __builtin_nontemporal_store(res, &out_f32[(size_t)nodec * DIM + d]);
            else      __builtin_nontemporal_store(f2bf(res), &h_out_bf[(size_t)nodec * DIM + d]);
        }
    }
}

// ---------------- launch ----------------

extern "C" void kernel_launch(void* const* d_in, const int* in_sizes, int n_in,
                              void* d_out, int out_size, void* d_ws, size_t ws_size,
                              hipStream_t stream) {
    const float* x = (const float*)d_in[0];
    const int* ei = (const int*)d_in[1];
    const float* w_in = (const float*)d_in[2];
    const float* b_in = (const float*)d_in[3];
    const float* w_l = (const float*)d_in[4];
    const float* b_l = (const float*)d_in[5];
    const float* w_r = (const float*)d_in[6];
    const float* gamma = (const float*)d_in[7];
    const float* beta = (const float*)d_in[8];

    int n = in_sizes[0] / INDIM;
    int e = in_sizes[1] / 2;
    int L = in_sizes[4] / (DIM * DIM);
    const int* src = ei;
    const int* dst = ei + e;
    int nb = (n + BKN - 1) >> BKBITS;  // 128-node buckets (782 for N=100000)

    // workspace carve (~21.7 MB)
    char* w = (char*)d_ws;
    int* bcnt = (int*)w;               w += (size_t)NBMAX * 4;
    int* bbase = (int*)w;              w += (size_t)(NBMAX + 1) * 4;
    int* bcur = (int*)w;               w += (size_t)NBMAX * 4;
    int* row_ptr = (int*)w;            w += (size_t)(n + 1) * 4;
    int* esrc = (int*)w;               w += (size_t)e * 4;
    unsigned short* h_A = (unsigned short*)w;  w += (size_t)n * DIM * 2;
    unsigned short* h_B = (unsigned short*)w;  w += (size_t)n * DIM * 2;
    // packed (E*4 = 8 MB) aliases h_A+h_B (12.8 MB): dead before input_proj
    unsigned* packed = (unsigned*)h_A;

    int nbE = (e + EPB - 1) / EPB;

    hipMemsetAsync(bcnt, 0, (size_t)nb * 4, stream);
    bucket_count_kernel<<<nbE, 256, 0, stream>>>(dst, bcnt, e, nb);
    bucket_scan_kernel<<<1, 1024, 0, stream>>>(bcnt, bbase, bcur, row_ptr, nb, n, e);
    bucket_fill_kernel<<<nbE, 256, 0, stream>>>(src, dst, bcur, packed, e, nb);
    csr_build_kernel<<<nb, 256, 0, stream>>>(packed, bbase, row_ptr, esrc, n);

    input_proj_kernel<<<(n * DIM + 255) / 256, 256, 0, stream>>>(x, w_in, b_in, h_A, n);

    // L=3: A->B, B->A, A->d_out
    unsigned short* bufs[2] = {h_A, h_B};
    int nbF = (n + 15) / 16;
    for (int i = 0; i < L; i++) {
        const unsigned short* hin = bufs[i & 1];
        unsigned short* hout = bufs[(i + 1) & 1];
        const float* wl = w_l + (size_t)i * DIM * DIM;
        const float* bl = b_l + (size_t)i * DIM;
        const float* wr = w_r + (size_t)i * DIM * DIM;
        if (i == L - 1)
            layer_fused_kernel<1><<<nbF, 64, 0, stream>>>(row_ptr, esrc, hin, nullptr,
                                                          (float*)d_out, wl, bl, wr,
                                                          gamma, beta, n);
        else
            layer_fused_kernel<0><<<nbF, 64, 0, stream>>>(row_ptr, esrc, hin, hout,
                                                          nullptr, wl, bl, wr,
                                                          gamma, beta, n);
    }
}